// Round 4
// baseline (115.424 us; speedup 1.0000x reference)
//
#include <hip/hip_runtime.h>
#include <hip/hip_bf16.h>
#include <stdint.h>

// ---------------- problem constants ----------------
#define B_  4
#define N_  2048
#define C_  1024
#define E_  8
#define H_  512      // C/2

typedef __bf16 bf16x8 __attribute__((ext_vector_type(8)));
typedef __bf16 bf16x4 __attribute__((ext_vector_type(4)));
typedef float  f32x4  __attribute__((ext_vector_type(4)));

// ---------------- workspace layout (bytes) ----------------
#define WB_OFF   0ull
#define XB_OFF   (8ull*1024*1024)
#define GX_OFF   (XB_OFF + 32ull*1024*1024)
#define G_OFF    (GX_OFF + 4096ull*4)
#define BB_OFF   (G_OFF + 128ull)
#define H_OFF    (BB_OFF + 4096ull*4)

__device__ __forceinline__ void gload16(const void* g, void* l) {
  __builtin_amdgcn_global_load_lds((const __attribute__((address_space(1))) void*)g,
                                   (__attribute__((address_space(3))) void*)l, 16, 0, 0);
}

#define CFENCE() asm volatile("" ::: "memory")

// ---------------- 1. fused f32->bf16 cast (x & x_ir) + mean over N (x only) ----------------
// grid 512: blocks 0-255 -> x (with mean partials), 256-511 -> x_ir. 32 rows/block.
__global__ __launch_bounds__(256) void castmean_kernel(const float* __restrict__ x,
    const float* __restrict__ x_ir, __bf16* __restrict__ dst, float* __restrict__ gx) {
  __shared__ float red[256][8];
  int bi = blockIdx.x;
  int half = bi >> 8, rblk = bi & 255;
  const float* src = half ? x_ir : x;
  int t = threadIdx.x;
  int cg = t & 127, rg = t >> 7;
  int r0 = rblk * 32 + rg * 16;
  const float4* sp = (const float4*)(src + (size_t)r0 * C_) + cg * 2;
  __bf16* dp = dst + (size_t)half * ((size_t)B_ * N_ * C_) + (size_t)r0 * C_ + cg * 8;
  float s[8] = {};
  #pragma unroll 4
  for (int rr = 0; rr < 16; ++rr) {
    float4 a = sp[0], b4 = sp[1];
    bf16x8 o;
    o[0] = (__bf16)a.x; o[1] = (__bf16)a.y; o[2] = (__bf16)a.z; o[3] = (__bf16)a.w;
    o[4] = (__bf16)b4.x; o[5] = (__bf16)b4.y; o[6] = (__bf16)b4.z; o[7] = (__bf16)b4.w;
    *(bf16x8*)dp = o;
    s[0] += a.x; s[1] += a.y; s[2] += a.z; s[3] += a.w;
    s[4] += b4.x; s[5] += b4.y; s[6] += b4.z; s[7] += b4.w;
    sp += C_ / 4; dp += C_;
  }
  if (half == 0) {
    #pragma unroll
    for (int j = 0; j < 8; ++j) red[t][j] = s[j];
    __syncthreads();
    if (t < 128) {
      int b = (rblk * 32) >> 11;
      #pragma unroll
      for (int j = 0; j < 8; ++j)
        atomicAdd(&gx[b * C_ + cg * 8 + j], (red[t][j] + red[t + 128][j]) * (1.0f / N_));
    }
  }
}

// ---------------- 2. h = relu(gx @ gw1^T + gb1) ----------------
__global__ void h_kernel(const float* __restrict__ gx, const float* __restrict__ gw1,
                         const float* __restrict__ gb1, float* __restrict__ h) {
  __shared__ float sgx[B_][C_];
  int t = threadIdx.x;
  for (int i = t; i < B_ * C_; i += 256) sgx[i >> 10][i & 1023] = gx[i];
  __syncthreads();
  int j = blockIdx.x * 64 + (t >> 2);
  int b = t & 3;
  const float4* row = (const float4*)(gw1 + (size_t)j * C_);
  float acc = 0.f;
  #pragma unroll 4
  for (int c4 = 0; c4 < C_ / 4; ++c4) {
    float4 w = row[c4];
    acc += w.x * sgx[b][c4*4+0] + w.y * sgx[b][c4*4+1]
         + w.z * sgx[b][c4*4+2] + w.w * sgx[b][c4*4+3];
  }
  h[b * H_ + j] = fmaxf(acc + gb1[j], 0.f);
}

// ---------------- 3. logits + softmax -> g, plus bb = g @ be ----------------
__global__ __launch_bounds__(512) void gate2_kernel(const float* __restrict__ h,
    const float* __restrict__ gw2, const float* __restrict__ gb2,
    const float* __restrict__ be, float* __restrict__ g, float* __restrict__ bbp) {
  __shared__ float slog[B_ * E_];
  __shared__ float sg[B_ * E_];
  int t = threadIdx.x, wv = t >> 6, lane = t & 63;
  for (int q = 0; q < 4; ++q) {
    int pi = wv * 4 + q;
    int b = pi >> 3, e = pi & 7;
    float s = 0.f;
    for (int k = lane; k < H_; k += 64) s += h[b * H_ + k] * gw2[e * H_ + k];
    for (int off = 32; off; off >>= 1) s += __shfl_down(s, off);
    if (lane == 0) slog[pi] = s + gb2[e];
  }
  __syncthreads();
  if (t < B_) {
    float m = -1e30f;
    for (int e = 0; e < E_; ++e) m = fmaxf(m, slog[t * E_ + e]);
    float p[E_], sum = 0.f;
    for (int e = 0; e < E_; ++e) { p[e] = __expf(slog[t * E_ + e] - m); sum += p[e]; }
    float inv = 1.f / sum;
    for (int e = 0; e < E_; ++e) { sg[t * E_ + e] = p[e] * inv; g[t * E_ + e] = p[e] * inv; }
  }
  __syncthreads();
  #pragma unroll
  for (int q = 0; q < 8; ++q) {
    int i = q * 512 + t;
    int b = i >> 10, o = i & 1023;
    float s = 0.f;
    #pragma unroll
    for (int e = 0; e < E_; ++e) s += sg[b * E_ + e] * be[e * C_ + o];
    bbp[i] = s;
  }
}

// ---------------- 4. Wb[b] = sum_e g[b,e]*We[e] (bf16) ----------------
__global__ void wb_kernel(const float* __restrict__ g, const float* __restrict__ We,
                          __bf16* __restrict__ Wb) {
  size_t i = (size_t)blockIdx.x * 256 + threadIdx.x;
  int b = (int)(i >> 18);
  size_t oc4 = i & ((1u << 18) - 1);
  float gl[E_];
  #pragma unroll
  for (int e = 0; e < E_; ++e) gl[e] = g[b * E_ + e];
  const float4* src = (const float4*)We + oc4;
  float4 acc = make_float4(0.f, 0.f, 0.f, 0.f);
  #pragma unroll
  for (int e = 0; e < E_; ++e) {
    float4 w = src[(size_t)e * (C_ * C_ / 4)];
    acc.x += gl[e] * w.x; acc.y += gl[e] * w.y;
    acc.z += gl[e] * w.z; acc.w += gl[e] * w.w;
  }
  bf16x4 o;
  o[0] = (__bf16)acc.x; o[1] = (__bf16)acc.y; o[2] = (__bf16)acc.z; o[3] = (__bf16)acc.w;
  *(bf16x4*)(Wb + i * 4) = o;
}

// ---------------- 5. batched GEMM: out = Xb @ Wb^T + bb ----------------
// 256x256 tile, BK=64, 8 waves (2Mx4N). Slack-scheduled: stages u0,u1 in P0 and
// u2,u3 in P1 (deadlines >=2.5 phases later); ds_reads pipelined one phase ahead;
// 3 barriers/tile; counted vmcnt only.
#define NT 16   // K / 64

__global__ __launch_bounds__(512, 2) void moe_gemm(const __bf16* __restrict__ Xb,
    const __bf16* __restrict__ Wb, const float* __restrict__ bb, float* __restrict__ out) {
  __shared__ __attribute__((aligned(128))) char smem[2][65536];

  const int t = threadIdx.x;
  const int wid = t >> 6, lane = t & 63;
  const int wm = wid >> 2, wn = wid & 3;

  // XCD swizzle: one z-slice per XCD
  int f = blockIdx.x;
  int swz = (f & 7) * 32 + (f >> 3);
  int xb_ = swz & 3, yb_ = (swz >> 2) & 7, z = swz >> 5;
  int b = z & 3;
  const size_t mat = (size_t)N_ * C_;
  const __bf16* A  = Xb + (size_t)z * mat;
  const __bf16* Bm = Wb + (size_t)b * C_ * C_;
  float* O = out + (size_t)z * mat;
  const int row0 = yb_ * 256, col0 = xb_ * 256;

  // staging lane constants (pre-swizzled global src, linear LDS dest)
  const int lrow8 = lane >> 3;
  const int kblk  = ((lane & 7) ^ lrow8) << 3;

  // ds-read lane constants
  const int lr = lane & 15;
  const int swzk0 = (((lane >> 4) + 0) ^ (lane & 7)) << 4;
  const int swzk1 = (((lane >> 4) + 4) ^ (lane & 7)) << 4;

  auto stage = [&](int sid, int k0, char* buf) {
    #pragma unroll
    for (int j = 0; j < 2; ++j) {
      int u = wid * 2 + j;
      int rl0 = u * 8;
      if (sid == 0 || sid == 3) {           // A
        int hh = (sid == 3) ? 1 : 0;
        int row_u = rl0 + (rl0 & 64) + hh * 64;
        const __bf16* src = A + (size_t)(row0 + row_u + lrow8) * C_ + k0 + kblk;
        gload16(src, buf + row_u * 128);
      } else {                              // B
        int hh = (sid == 2) ? 1 : 0;
        int col_u = (rl0 & 31) + (rl0 >> 5) * 64 + hh * 32;
        const __bf16* src = Bm + (size_t)(col0 + col_u + lrow8) * C_ + k0 + kblk;
        gload16(src, buf + 32768 + col_u * 128);
      }
    }
  };

  f32x4 acc[8][4] = {};
  bf16x8 av[2][4][2];     // [pipeline buf][mq][ks]
  bf16x8 bv[2][2][2];     // [Bq][nq][ks]

  #define RD_A(buf_, Aq_, mq_) { \
    int rby = (wm * 128 + (Aq_) * 64 + (mq_) * 16 + lr) * 128; \
    av[buf_][mq_][0] = *(const bf16x8*)(rbA + rby + swzk0); \
    av[buf_][mq_][1] = *(const bf16x8*)(rbA + rby + swzk1); }
  #define RD_B(Bq_, nq_) { \
    int cby = (wn * 64 + (Bq_) * 32 + (nq_) * 16 + lr) * 128; \
    bv[Bq_][nq_][0] = *(const bf16x8*)(rbB + cby + swzk0); \
    bv[Bq_][nq_][1] = *(const bf16x8*)(rbB + cby + swzk1); }
  #define MFMA1(ab_, mq_, Bq_, nq_) { \
    acc[(ab_)*4+(mq_)][(Bq_)*2+(nq_)] = __builtin_amdgcn_mfma_f32_16x16x32_bf16( \
        av[ab_][mq_][0], bv[Bq_][nq_][0], acc[(ab_)*4+(mq_)][(Bq_)*2+(nq_)], 0, 0, 0); \
    acc[(ab_)*4+(mq_)][(Bq_)*2+(nq_)] = __builtin_amdgcn_mfma_f32_16x16x32_bf16( \
        av[ab_][mq_][1], bv[Bq_][nq_][1], acc[(ab_)*4+(mq_)][(Bq_)*2+(nq_)], 0, 0, 0); }

  // prologue: stage all 4 units of tile 0; need u0,u1 (P0 reads) + u2 (B1 lookahead)
  #pragma unroll
  for (int sid = 0; sid < 4; ++sid) stage(sid, 0, smem[0]);
  asm volatile("s_waitcnt vmcnt(2)" ::: "memory");
  __builtin_amdgcn_s_barrier();
  CFENCE();

  for (int kt = 0; kt < NT; ++kt) {
    const char* rbA = smem[kt & 1];
    const char* rbB = rbA + 32768;
    char* wbuf = smem[(kt + 1) & 1];
    const bool more = (kt + 1 < NT);
    const int knext = (kt + 1) * 64;

    // ---- P0: stage u0,u1 | read A0,B0 | MFMA A0xB0 (+lookahead read B1) ----
    if (more) { stage(0, knext, wbuf); stage(1, knext, wbuf); }
    RD_A(0, 0, 0) RD_B(0, 0) RD_A(0, 0, 1) RD_B(0, 1) RD_A(0, 0, 2) RD_A(0, 0, 3)
    __builtin_amdgcn_s_setprio(1);
    MFMA1(0, 0, 0, 0) MFMA1(0, 0, 0, 1)
    RD_B(1, 0) RD_B(1, 1)                          // lookahead for P1
    MFMA1(0, 1, 0, 0) MFMA1(0, 1, 0, 1)
    MFMA1(0, 2, 0, 0) MFMA1(0, 2, 0, 1)
    MFMA1(0, 3, 0, 0) MFMA1(0, 3, 0, 1)
    __builtin_amdgcn_s_setprio(0);
    if (more) asm volatile("s_waitcnt vmcnt(4)" ::: "memory");   // u3(cur) done
    else      asm volatile("s_waitcnt vmcnt(0)" ::: "memory");
    __builtin_amdgcn_s_barrier();
    CFENCE();

    // ---- P1: stage u2,u3 | MFMA A0xB1 (+lookahead read A1) ----
    if (more) { stage(2, knext, wbuf); stage(3, knext, wbuf); }
    __builtin_amdgcn_s_setprio(1);
    MFMA1(0, 0, 1, 0) MFMA1(0, 0, 1, 1)
    RD_A(1, 1, 0) RD_A(1, 1, 1)                    // lookahead for P23
    MFMA1(0, 1, 1, 0) MFMA1(0, 1, 1, 1)
    RD_A(1, 1, 2) RD_A(1, 1, 3)
    MFMA1(0, 2, 1, 0) MFMA1(0, 2, 1, 1)
    MFMA1(0, 3, 1, 0) MFMA1(0, 3, 1, 1)
    __builtin_amdgcn_s_setprio(0);
    __builtin_amdgcn_s_barrier();
    CFENCE();

    // ---- P23: MFMA A1xB0, A1xB1 ----
    __builtin_amdgcn_s_setprio(1);
    MFMA1(1, 0, 0, 0) MFMA1(1, 0, 0, 1) MFMA1(1, 1, 0, 0) MFMA1(1, 1, 0, 1)
    MFMA1(1, 2, 0, 0) MFMA1(1, 2, 0, 1) MFMA1(1, 3, 0, 0) MFMA1(1, 3, 0, 1)
    MFMA1(1, 0, 1, 0) MFMA1(1, 0, 1, 1) MFMA1(1, 1, 1, 0) MFMA1(1, 1, 1, 1)
    MFMA1(1, 2, 1, 0) MFMA1(1, 2, 1, 1) MFMA1(1, 3, 1, 0) MFMA1(1, 3, 1, 1)
    __builtin_amdgcn_s_setprio(0);
    if (more) asm volatile("s_waitcnt vmcnt(2)" ::: "memory");   // u0,u1,u2(next) done
    __builtin_amdgcn_s_barrier();
    CFENCE();
  }

  // ---- coalesced epilogue: per-wave LDS transpose (16 x 68 f32) ----
  float* eb = (float*)(smem[0]) + wid * (16 * 68);
  const int er = lane >> 4;
  const f32x4 bias4 = *(const f32x4*)(bb + b * C_ + col0 + wn * 64 + lr * 4);

  #pragma unroll
  for (int m = 0; m < 8; ++m) {
    #pragma unroll
    for (int n = 0; n < 4; ++n) {
      f32x4 v = acc[m][n];
      #pragma unroll
      for (int r = 0; r < 4; ++r)
        eb[(er * 4 + r) * 68 + n * 16 + lr] = v[r];
    }
    asm volatile("s_waitcnt lgkmcnt(0)" ::: "memory");
    __builtin_amdgcn_sched_barrier(0);
    #pragma unroll
    for (int j = 0; j < 4; ++j) {
      int row = j * 4 + er;
      f32x4 v = *(const f32x4*)(eb + row * 68 + lr * 4);
      v[0] += bias4[0]; v[1] += bias4[1]; v[2] += bias4[2]; v[3] += bias4[3];
      int grow = row0 + wm * 128 + m * 16 + row;
      int gcol = col0 + wn * 64 + lr * 4;
      *(f32x4*)(O + (size_t)grow * C_ + gcol) = v;
    }
  }
}

// ---------------- launcher ----------------
extern "C" void kernel_launch(void* const* d_in, const int* in_sizes, int n_in,
                              void* d_out, int out_size, void* d_ws, size_t ws_size,
                              hipStream_t stream) {
  const float* x    = (const float*)d_in[0];
  const float* x_ir = (const float*)d_in[1];
  const float* We   = (const float*)d_in[2];
  const float* be   = (const float*)d_in[3];
  const float* gw1  = (const float*)d_in[4];
  const float* gb1  = (const float*)d_in[5];
  const float* gw2  = (const float*)d_in[6];
  const float* gb2  = (const float*)d_in[7];
  float* out = (float*)d_out;

  char* ws = (char*)d_ws;
  __bf16* Wb  = (__bf16*)(ws + WB_OFF);
  __bf16* Xb  = (__bf16*)(ws + XB_OFF);
  float*  gx  = (float*)(ws + GX_OFF);
  float*  g   = (float*)(ws + G_OFF);
  float*  bbp = (float*)(ws + BB_OFF);
  float*  h   = (float*)(ws + H_OFF);

  hipMemsetAsync(gx, 0, B_ * C_ * sizeof(float), stream);

  castmean_kernel<<<512, 256, 0, stream>>>(x, x_ir, Xb, gx);
  h_kernel<<<8, 256, 0, stream>>>(gx, gw1, gb1, h);
  gate2_kernel<<<1, 512, 0, stream>>>(h, gw2, gb2, be, g, bbp);
  wb_kernel<<<4096, 256, 0, stream>>>(g, We, Wb);

  moe_gemm<<<256, 512, 0, stream>>>(Xb, Wb, bbp, out);
}